// Round 1
// baseline (2446.542 us; speedup 1.0000x reference)
//
#include <hip/hip_runtime.h>

typedef __bf16 bf16;
typedef __attribute__((ext_vector_type(8))) __bf16 bf16x8;
typedef __attribute__((ext_vector_type(4))) float f32x4;

__device__ __forceinline__ void gload_lds16(const void* g, void* l) {
  __builtin_amdgcn_global_load_lds(
      (const __attribute__((address_space(1))) void*)g,
      (__attribute__((address_space(3))) void*)l, 16, 0, 0);
}

__device__ __forceinline__ float sigmoidf_(float x) { return 1.0f / (1.0f + expf(-x)); }

// C = A @ B^T, A:[M x K] bf16 (lda), Bw:[N x K] bf16 (ldb), C:[M x N] f32 (ldc)
// MODE 0: plain f32 store. MODE 1: out-projection epilogue:
//   v = sigmoid(acc + outb[n]); scatter to dout (notes layout) and bf16 note into anote.
template<int BM, int BN, int WM, int WN, int MODE>
__global__ __launch_bounds__(WM * WN * 64)
void gemm_bt(const bf16* __restrict__ A, int lda,
             const bf16* __restrict__ Bw, int ldb,
             float* __restrict__ C, int ldc,
             int K,
             const float* __restrict__ outb, float* __restrict__ dout,
             bf16* __restrict__ anote, int nstep) {
  constexpr int BK = 64;
  constexpr int THREADS = WM * WN * 64;
  constexpr int SM = BM / WM, SN = BN / WN;
  constexpr int FM = SM / 16, FN = SN / 16;

  __shared__ __align__(16) bf16 lsA[BM * BK];
  __shared__ __align__(16) bf16 lsB[BN * BK];

  const int tid = threadIdx.x;
  const int lane = tid & 63;
  const int wave = tid >> 6;
  const int wm = wave / WN, wn = wave % WN;
  const int m0 = blockIdx.y * BM;
  const int n0 = blockIdx.x * BN;

  f32x4 acc[FM][FN] = {};

  const bf16* gA = A + (size_t)m0 * lda;
  const bf16* gB = Bw + (size_t)n0 * ldb;

  for (int k0 = 0; k0 < K; k0 += BK) {
    // stage A tile [BM x BK] and B tile [BN x BK] (K-contiguous rows) into LDS
#pragma unroll
    for (int i = 0; i < (BM * 8) / THREADS; ++i) {
      int idx = i * THREADS + tid;
      gload_lds16(gA + (size_t)(idx >> 3) * lda + k0 + (idx & 7) * 8, &lsA[idx * 8]);
    }
#pragma unroll
    for (int i = 0; i < (BN * 8) / THREADS; ++i) {
      int idx = i * THREADS + tid;
      gload_lds16(gB + (size_t)(idx >> 3) * ldb + k0 + (idx & 7) * 8, &lsB[idx * 8]);
    }
    __syncthreads();

#pragma unroll
    for (int kk = 0; kk < BK; kk += 32) {
      bf16x8 av[FM], bv[FN];
#pragma unroll
      for (int i = 0; i < FM; ++i)
        av[i] = *(const bf16x8*)&lsA[(wm * SM + i * 16 + (lane & 15)) * BK + kk + (lane >> 4) * 8];
#pragma unroll
      for (int j = 0; j < FN; ++j)
        bv[j] = *(const bf16x8*)&lsB[(wn * SN + j * 16 + (lane & 15)) * BK + kk + (lane >> 4) * 8];
#pragma unroll
      for (int i = 0; i < FM; ++i)
#pragma unroll
        for (int j = 0; j < FN; ++j)
          acc[i][j] = __builtin_amdgcn_mfma_f32_16x16x32_bf16(av[i], bv[j], acc[i][j], 0, 0, 0);
    }
    __syncthreads();
  }

#pragma unroll
  for (int i = 0; i < FM; ++i) {
#pragma unroll
    for (int j = 0; j < FN; ++j) {
      const int col = n0 + wn * SN + j * 16 + (lane & 15);
      const int rbase = m0 + wm * SM + i * 16 + ((lane >> 4) << 2);
#pragma unroll
      for (int r = 0; r < 4; ++r) {
        const int row = rbase + r;
        float v = acc[i][j][r];
        if constexpr (MODE == 0) {
          C[(size_t)row * ldc + col] = v;
        } else {
          v = sigmoidf_(v + outb[col]);
          const int l = row >> 8, b = row & 255;
          dout[((size_t)(b * 256 + l * 16 + nstep)) * 512 + col] = v;
          anote[(size_t)row * 1536 + col] = (bf16)v;
        }
      }
    }
  }
}

// ---------------- elementwise / packing kernels ----------------

__global__ void conv_f32_bf16(const float* __restrict__ src, bf16* __restrict__ dst, int n) {
  int idx = blockIdx.x * 256 + threadIdx.x;
  if (idx < n) dst[idx] = (bf16)src[idx];
}

// Wd[4096][1536]: cols 0:512 = dec_Wih[:,1024:1536] (note part), 512:1536 = dec_Whh
__global__ void pack_w_dec(const float* __restrict__ wih, const float* __restrict__ whh,
                           bf16* __restrict__ dst) {
  int idx = blockIdx.x * 256 + threadIdx.x;  // 4096*1536
  int r = idx / 1536, c = idx - r * 1536;
  float v = (c < 512) ? wih[(size_t)r * 1536 + 1024 + c] : whh[(size_t)r * 1024 + (c - 512)];
  dst[idx] = (bf16)v;
}

// We[4096][1024] = dec_Wih[:, 0:1024] (emb part)
__global__ void pack_w_emb(const float* __restrict__ wih, bf16* __restrict__ dst) {
  int idx = blockIdx.x * 256 + threadIdx.x;  // 4096*1024
  int r = idx >> 10, c = idx & 1023;
  dst[idx] = (bf16)wih[(size_t)r * 1536 + c];
}

// Zb[m=l*256+b][k] = z[b, 16*l, 0, k]  (4096 x 512 bf16)
__global__ void pack_zb(const float* __restrict__ z, bf16* __restrict__ dst) {
  int idx = blockIdx.x * 256 + threadIdx.x;  // 4096*512
  int m = idx >> 9, k = idx & 511;
  int l = m >> 8, b = m & 255;
  dst[idx] = (bf16)z[((size_t)b * 256 + 16 * l) * 512 + k];
}

// zero conductor c-state (f32) and h0 (bf16)
__global__ void init_cond(float* __restrict__ cc, bf16* __restrict__ hz0) {
  int idx = blockIdx.x * 256 + threadIdx.x;  // 256*1024
  cc[idx] = 0.f;
  hz0[idx] = (bf16)0.f;
}

// Abuf[m][0:512] = 0 (note0); Abuf[m][512+j] = bf16(dec_h0[m*1024+j]); cdec = dec_c0 copy
__global__ void init_state(const float* __restrict__ h0, const float* __restrict__ c0,
                           bf16* __restrict__ Abuf, float* __restrict__ cdec) {
  int idx = blockIdx.x * 256 + threadIdx.x;  // 4096*1536
  int m = idx / 1536, c = idx - m * 1536;
  if (c < 512) {
    Abuf[idx] = (bf16)0.f;
  } else {
    int j = c - 512;
    size_t s = (size_t)m * 1024 + j;
    Abuf[idx] = (bf16)h0[s];
    cdec[s] = c0[s];
  }
}

// conductor LSTM cell for level l. G: h@Whh.T gates [256x4096]; Xz: z@Wih.T for all levels.
__global__ void cond_cell(const float* __restrict__ G, const float* __restrict__ Xz,
                          const float* __restrict__ bih, const float* __restrict__ bhh,
                          float* __restrict__ cc, bf16* __restrict__ emb, int l) {
  int idx = blockIdx.x * 256 + threadIdx.x;  // 256*1024
  int b = idx >> 10, j = idx & 1023;
  const float* g = G + (size_t)b * 4096;
  const float* x = Xz + ((size_t)(l * 256 + b)) * 4096;
  float gi = g[j] + x[j] + bih[j] + bhh[j];
  float gf = g[j + 1024] + x[j + 1024] + bih[j + 1024] + bhh[j + 1024];
  float gg = g[j + 2048] + x[j + 2048] + bih[j + 2048] + bhh[j + 2048];
  float go = g[j + 3072] + x[j + 3072] + bih[j + 3072] + bhh[j + 3072];
  float c = sigmoidf_(gf) * cc[idx] + sigmoidf_(gi) * tanhf(gg);
  cc[idx] = c;
  emb[((size_t)(l * 256 + b)) * 1024 + j] = (bf16)(sigmoidf_(go) * tanhf(c));
}

// decoder LSTM cell (all 16 levels batched, m = l*256+b)
__global__ void dec_cell(const float* __restrict__ G, const float* __restrict__ E,
                         const float* __restrict__ bih, const float* __restrict__ bhh,
                         float* __restrict__ cdec, bf16* __restrict__ Abuf) {
  int idx = blockIdx.x * 256 + threadIdx.x;  // 4096*1024
  int m = idx >> 10, j = idx & 1023;
  const float* g = G + (size_t)m * 4096;
  const float* e = E + (size_t)m * 4096;
  float gi = g[j] + e[j] + bih[j] + bhh[j];
  float gf = g[j + 1024] + e[j + 1024] + bih[j + 1024] + bhh[j + 1024];
  float gg = g[j + 2048] + e[j + 2048] + bih[j + 2048] + bhh[j + 2048];
  float go = g[j + 3072] + e[j + 3072] + bih[j + 3072] + bhh[j + 3072];
  float c = sigmoidf_(gf) * cdec[idx] + sigmoidf_(gi) * tanhf(gg);
  cdec[idx] = c;
  float h = sigmoidf_(go) * tanhf(c);
  Abuf[(size_t)m * 1536 + 512 + j] = (bf16)h;
}

extern "C" void kernel_launch(void* const* d_in, const int* in_sizes, int n_in,
                              void* d_out, int out_size, void* d_ws, size_t ws_size,
                              hipStream_t stream) {
  const float* z        = (const float*)d_in[0];
  const float* dec_h0   = (const float*)d_in[1];
  const float* dec_c0   = (const float*)d_in[2];
  const float* cond_Wih = (const float*)d_in[5];
  const float* cond_Whh = (const float*)d_in[6];
  const float* cond_bih = (const float*)d_in[7];
  const float* cond_bhh = (const float*)d_in[8];
  const float* dec_Wih  = (const float*)d_in[9];
  const float* dec_Whh  = (const float*)d_in[10];
  const float* dec_bih  = (const float*)d_in[11];
  const float* dec_bhh  = (const float*)d_in[12];
  const float* out_W    = (const float*)d_in[13];
  const float* out_b    = (const float*)d_in[14];
  float* out = (float*)d_out;

  char* ws = (char*)d_ws;
  size_t off = 0;
  auto alloc = [&](size_t bytes) {
    void* p = ws + off;
    off += (bytes + 255) & ~(size_t)255;
    return p;
  };
  float* E    = (float*)alloc(4096ull * 4096 * 4);  // Xz during conductor, then emb contribution
  float* G    = (float*)alloc(4096ull * 4096 * 4);  // gates scratch
  float* cdec = (float*)alloc(4096ull * 1024 * 4);
  bf16* Abuf  = (bf16*)alloc(4096ull * 1536 * 2);   // [note(512) | h(1024)] bf16
  bf16* Wd    = (bf16*)alloc(4096ull * 1536 * 2);   // [Wih_note | Whh] bf16
  bf16* We    = (bf16*)alloc(4096ull * 1024 * 2);   // Wih_emb bf16
  bf16* Wcih  = (bf16*)alloc(4096ull * 512 * 2);
  bf16* Wchh  = (bf16*)alloc(4096ull * 1024 * 2);
  bf16* Wo    = (bf16*)alloc(512ull * 1024 * 2);
  float* cc   = (float*)alloc(256ull * 1024 * 4);
  bf16* emb   = (bf16*)alloc(4096ull * 1024 * 2);   // conductor h per level, bf16
  bf16* Zb    = (bf16*)alloc(4096ull * 512 * 2);
  bf16* hz0   = (bf16*)alloc(256ull * 1024 * 2);

  dim3 b256(256);

  // weight packing (bf16)
  conv_f32_bf16<<<(4096 * 512 + 255) / 256, b256, 0, stream>>>(cond_Wih, Wcih, 4096 * 512);
  conv_f32_bf16<<<(4096 * 1024 + 255) / 256, b256, 0, stream>>>(cond_Whh, Wchh, 4096 * 1024);
  conv_f32_bf16<<<(512 * 1024 + 255) / 256, b256, 0, stream>>>(out_W, Wo, 512 * 1024);
  pack_w_dec<<<4096 * 1536 / 256, b256, 0, stream>>>(dec_Wih, dec_Whh, Wd);
  pack_w_emb<<<4096 * 1024 / 256, b256, 0, stream>>>(dec_Wih, We);
  pack_zb<<<4096 * 512 / 256, b256, 0, stream>>>(z, Zb);
  init_cond<<<256 * 1024 / 256, b256, 0, stream>>>(cc, hz0);
  init_state<<<4096 * 1536 / 256, b256, 0, stream>>>(dec_h0, dec_c0, Abuf, cdec);

  // Xz = Zb @ Wcih^T for all levels at once  [4096 x 4096] into E buffer
  gemm_bt<128, 128, 2, 2, 0><<<dim3(32, 32), dim3(256), 0, stream>>>(
      Zb, 512, Wcih, 512, E, 4096, 512, nullptr, nullptr, nullptr, 0);

  // conductor chain: 16 sequential levels, only h@Whh.T per level
  for (int l = 0; l < 16; ++l) {
    const bf16* hprev = (l == 0) ? hz0 : (emb + (size_t)(l - 1) * 256 * 1024);
    gemm_bt<32, 128, 1, 2, 0><<<dim3(4096 / 128, 256 / 32), dim3(128), 0, stream>>>(
        hprev, 1024, Wchh, 1024, G, 4096, 1024, nullptr, nullptr, nullptr, 0);
    cond_cell<<<256 * 1024 / 256, b256, 0, stream>>>(G, E, cond_bih, cond_bhh, cc, emb, l);
  }

  // E = emb @ We^T + (biases added in dec_cell)   [4096 x 4096]
  gemm_bt<128, 128, 2, 2, 0><<<dim3(32, 32), dim3(256), 0, stream>>>(
      emb, 1024, We, 1024, E, 4096, 1024, nullptr, nullptr, nullptr, 0);

  // 16 autoregressive decoder steps, all 16 levels batched (M = 4096)
  for (int n = 0; n < 16; ++n) {
    gemm_bt<128, 128, 2, 2, 0><<<dim3(32, 32), dim3(256), 0, stream>>>(
        Abuf, 1536, Wd, 1536, G, 4096, 1536, nullptr, nullptr, nullptr, 0);
    dec_cell<<<4096 * 1024 / 256, b256, 0, stream>>>(G, E, dec_bih, dec_bhh, cdec, Abuf);
    gemm_bt<128, 64, 2, 2, 1><<<dim3(512 / 64, 4096 / 128), dim3(256), 0, stream>>>(
        Abuf + 512, 1536, Wo, 1024, nullptr, 0, 1024, out_b, out, Abuf, n);
  }
}

// Round 2
// 1978.892 us; speedup vs baseline: 1.2363x; 1.2363x over previous
//
#include <hip/hip_runtime.h>

typedef __bf16 bf16;
typedef __attribute__((ext_vector_type(8))) __bf16 bf16x8;
typedef __attribute__((ext_vector_type(4))) float f32x4;

__device__ __forceinline__ void gload_lds16(const void* g, void* l) {
  __builtin_amdgcn_global_load_lds(
      (const __attribute__((address_space(1))) void*)g,
      (__attribute__((address_space(3))) void*)l, 16, 0, 0);
}

__device__ __forceinline__ float sigmoidf_(float x) { return 1.0f / (1.0f + expf(-x)); }

// ---------------------------------------------------------------------------
// Plain A@B^T GEMM. MODE 0: f32 store. MODE 1: out-projection epilogue
// (sigmoid + scatter to notes + bf16 note feedback). MODE 2: bf16 store.
// ---------------------------------------------------------------------------
template<int BM, int BN, int WM, int WN, int MODE>
__global__ __launch_bounds__(WM * WN * 64)
void gemm_bt(const bf16* __restrict__ A, int lda,
             const bf16* __restrict__ Bw, int ldb,
             float* __restrict__ C, int ldc,
             int K,
             const float* __restrict__ outb, float* __restrict__ dout,
             bf16* __restrict__ anote, int nstep) {
  constexpr int BK = 64;
  constexpr int THREADS = WM * WN * 64;
  constexpr int SM = BM / WM, SN = BN / WN;
  constexpr int FM = SM / 16, FN = SN / 16;

  __shared__ __align__(16) bf16 lsA[BM * BK];
  __shared__ __align__(16) bf16 lsB[BN * BK];

  const int tid = threadIdx.x;
  const int lane = tid & 63;
  const int wave = tid >> 6;
  const int wm = wave / WN, wn = wave % WN;
  const int m0 = blockIdx.y * BM;
  const int n0 = blockIdx.x * BN;

  f32x4 acc[FM][FN] = {};

  const bf16* gA = A + (size_t)m0 * lda;
  const bf16* gB = Bw + (size_t)n0 * ldb;

  for (int k0 = 0; k0 < K; k0 += BK) {
#pragma unroll
    for (int i = 0; i < (BM * 8) / THREADS; ++i) {
      int idx = i * THREADS + tid;
      gload_lds16(gA + (size_t)(idx >> 3) * lda + k0 + (idx & 7) * 8, &lsA[idx * 8]);
    }
#pragma unroll
    for (int i = 0; i < (BN * 8) / THREADS; ++i) {
      int idx = i * THREADS + tid;
      gload_lds16(gB + (size_t)(idx >> 3) * ldb + k0 + (idx & 7) * 8, &lsB[idx * 8]);
    }
    __syncthreads();

#pragma unroll
    for (int kk = 0; kk < BK; kk += 32) {
      bf16x8 av[FM], bv[FN];
#pragma unroll
      for (int i = 0; i < FM; ++i)
        av[i] = *(const bf16x8*)&lsA[(wm * SM + i * 16 + (lane & 15)) * BK + kk + (lane >> 4) * 8];
#pragma unroll
      for (int j = 0; j < FN; ++j)
        bv[j] = *(const bf16x8*)&lsB[(wn * SN + j * 16 + (lane & 15)) * BK + kk + (lane >> 4) * 8];
#pragma unroll
      for (int i = 0; i < FM; ++i)
#pragma unroll
        for (int j = 0; j < FN; ++j)
          acc[i][j] = __builtin_amdgcn_mfma_f32_16x16x32_bf16(av[i], bv[j], acc[i][j], 0, 0, 0);
    }
    __syncthreads();
  }

#pragma unroll
  for (int i = 0; i < FM; ++i) {
#pragma unroll
    for (int j = 0; j < FN; ++j) {
      const int col = n0 + wn * SN + j * 16 + (lane & 15);
      const int rbase = m0 + wm * SM + i * 16 + ((lane >> 4) << 2);
#pragma unroll
      for (int r = 0; r < 4; ++r) {
        const int row = rbase + r;
        float v = acc[i][j][r];
        if constexpr (MODE == 0) {
          C[(size_t)row * ldc + col] = v;
        } else if constexpr (MODE == 2) {
          ((bf16*)C)[(size_t)row * ldc + col] = (bf16)v;
        } else {
          v = sigmoidf_(v + outb[col]);
          const int l = row >> 8, b = row & 255;
          dout[((size_t)(b * 256 + l * 16 + nstep)) * 512 + col] = v;
          anote[(size_t)row * 1536 + col] = (bf16)v;
        }
      }
    }
  }
}

// ---------------------------------------------------------------------------
// Fused GEMM + LSTM cell. Weight rows are packed in P order:
//   n' = (j>>4)*64 + gate*16 + (j&15)   (gate in i,f,g,o order)
// so each 16-wide MFMA N-fragment is one gate and the 4 gates of a j live in
// the SAME lane across 4 accumulators. X (bf16, [rows x 4H] in P layout) is
// the precomputed input contribution; bias is bih+bhh in P layout.
//   c' = sig(f)*c + sig(i)*tanh(g);  h = sig(o)*tanh(c')  -> hout (bf16)
// ---------------------------------------------------------------------------
template<int BM, int BJ, int WM, int WJ>
__global__ __launch_bounds__(WM * WJ * 64, 2)
void gemm_cell(const bf16* __restrict__ A, int lda,
               const bf16* __restrict__ Bw,
               const bf16* __restrict__ X,
               const float* __restrict__ bias,
               float* __restrict__ cst,
               bf16* __restrict__ hout, int ldh, int K) {
  constexpr int BK = 64;
  constexpr int THREADS = WM * WJ * 64;
  constexpr int BN = BJ * 64;          // gate-cols per block (BJ j16-groups x 4 gates)
  constexpr int SM = BM / WM;
  constexpr int TJ = BJ / WJ;          // j16-groups per wave
  constexpr int FM = SM / 16;

  __shared__ __align__(16) bf16 lsA[BM * BK];
  __shared__ __align__(16) bf16 lsB[BN * BK];

  const int tid = threadIdx.x;
  const int lane = tid & 63;
  const int wave = tid >> 6;
  const int wm = wave / WJ, wj = wave % WJ;
  const int m0 = blockIdx.y * BM;
  const int qb = blockIdx.x * BJ;      // j16 base

  f32x4 acc[FM][TJ][4] = {};

  const bf16* gA = A + (size_t)m0 * lda;
  const bf16* gB = Bw + (size_t)(qb * 64) * K;

  for (int k0 = 0; k0 < K; k0 += BK) {
#pragma unroll
    for (int i = 0; i < (BM * 8) / THREADS; ++i) {
      int idx = i * THREADS + tid;
      gload_lds16(gA + (size_t)(idx >> 3) * lda + k0 + (idx & 7) * 8, &lsA[idx * 8]);
    }
#pragma unroll
    for (int i = 0; i < (BN * 8) / THREADS; ++i) {
      int idx = i * THREADS + tid;
      gload_lds16(gB + (size_t)(idx >> 3) * K + k0 + (idx & 7) * 8, &lsB[idx * 8]);
    }
    __syncthreads();

#pragma unroll
    for (int kk = 0; kk < BK; kk += 32) {
      bf16x8 av[FM], bv[TJ][4];
#pragma unroll
      for (int i = 0; i < FM; ++i)
        av[i] = *(const bf16x8*)&lsA[(wm * SM + i * 16 + (lane & 15)) * BK + kk + (lane >> 4) * 8];
#pragma unroll
      for (int t = 0; t < TJ; ++t)
#pragma unroll
        for (int g = 0; g < 4; ++g)
          bv[t][g] = *(const bf16x8*)
              &lsB[((wj * TJ + t) * 64 + g * 16 + (lane & 15)) * BK + kk + (lane >> 4) * 8];
#pragma unroll
      for (int i = 0; i < FM; ++i)
#pragma unroll
        for (int t = 0; t < TJ; ++t)
#pragma unroll
          for (int g = 0; g < 4; ++g)
            acc[i][t][g] =
                __builtin_amdgcn_mfma_f32_16x16x32_bf16(av[i], bv[t][g], acc[i][t][g], 0, 0, 0);
    }
    __syncthreads();
  }

  // fused LSTM-cell epilogue
#pragma unroll
  for (int i = 0; i < FM; ++i) {
#pragma unroll
    for (int t = 0; t < TJ; ++t) {
      const int q = qb + wj * TJ + t;
      const int jj = lane & 15;
      const int j = q * 16 + jj;
      const int rbase = m0 + wm * SM + i * 16 + ((lane >> 4) << 2);
      const float b0 = bias[q * 64 + jj];
      const float b1 = bias[q * 64 + 16 + jj];
      const float b2 = bias[q * 64 + 32 + jj];
      const float b3 = bias[q * 64 + 48 + jj];
#pragma unroll
      for (int r = 0; r < 4; ++r) {
        const int row = rbase + r;
        const bf16* xp = X + (size_t)row * 4096 + q * 64 + jj;
        const float gi = acc[i][t][0][r] + (float)xp[0]  + b0;
        const float gf = acc[i][t][1][r] + (float)xp[16] + b1;
        const float gg = acc[i][t][2][r] + (float)xp[32] + b2;
        const float go = acc[i][t][3][r] + (float)xp[48] + b3;
        const size_t ci = (size_t)row * 1024 + j;
        const float c = sigmoidf_(gf) * cst[ci] + sigmoidf_(gi) * tanhf(gg);
        cst[ci] = c;
        hout[(size_t)row * ldh + j] = (bf16)(sigmoidf_(go) * tanhf(c));
      }
    }
  }
}

// ---------------- packing / init kernels ----------------

__global__ void conv_f32_bf16(const float* __restrict__ src, bf16* __restrict__ dst, int n) {
  int idx = blockIdx.x * 256 + threadIdx.x;
  if (idx < n) dst[idx] = (bf16)src[idx];
}

// P-permuted row index: n' -> source row r = gate*1024 + q*16 + jj
__device__ __forceinline__ int p_src_row(int n) {
  int q = n >> 6, gate = (n >> 4) & 3, jj = n & 15;
  return gate * 1024 + q * 16 + jj;
}

// Wd[n'][1536]: cols 0:512 = dec_Wih[r, 1024:1536] (note), 512:1536 = dec_Whh[r]
__global__ void pack_w_dec(const float* __restrict__ wih, const float* __restrict__ whh,
                           bf16* __restrict__ dst) {
  int idx = blockIdx.x * 256 + threadIdx.x;  // 4096*1536
  int n = idx / 1536, c = idx - n * 1536;
  int r = p_src_row(n);
  float v = (c < 512) ? wih[(size_t)r * 1536 + 1024 + c] : whh[(size_t)r * 1024 + (c - 512)];
  dst[idx] = (bf16)v;
}

// We[n'][1024] = dec_Wih[r, 0:1024] (emb part)
__global__ void pack_w_emb(const float* __restrict__ wih, bf16* __restrict__ dst) {
  int idx = blockIdx.x * 256 + threadIdx.x;  // 4096*1024
  int n = idx >> 10, c = idx & 1023;
  dst[idx] = (bf16)wih[(size_t)p_src_row(n) * 1536 + c];
}

// generic P-permuted pack: dst[n'][Kw] = src[r][Kw]
__global__ void pack_w_perm(const float* __restrict__ src, bf16* __restrict__ dst, int Kw) {
  int idx = blockIdx.x * 256 + threadIdx.x;  // 4096*Kw
  int n = idx / Kw, c = idx - n * Kw;
  dst[idx] = (bf16)src[(size_t)p_src_row(n) * Kw + c];
}

__global__ void pack_bias(const float* __restrict__ bih, const float* __restrict__ bhh,
                          float* __restrict__ dst) {
  int n = blockIdx.x * 256 + threadIdx.x;  // 4096
  int r = p_src_row(n);
  dst[n] = bih[r] + bhh[r];
}

// Zb[m=l*256+b][k] = z[b, 16*l, 0, k]  (4096 x 512 bf16)
__global__ void pack_zb(const float* __restrict__ z, bf16* __restrict__ dst) {
  int idx = blockIdx.x * 256 + threadIdx.x;  // 4096*512
  int m = idx >> 9, k = idx & 511;
  int l = m >> 8, b = m & 255;
  dst[idx] = (bf16)z[((size_t)b * 256 + 16 * l) * 512 + k];
}

__global__ void init_cond(float* __restrict__ cc, bf16* __restrict__ hz0) {
  int idx = blockIdx.x * 256 + threadIdx.x;  // 256*1024
  cc[idx] = 0.f;
  hz0[idx] = (bf16)0.f;
}

__global__ void init_state(const float* __restrict__ h0, const float* __restrict__ c0,
                           bf16* __restrict__ Abuf, float* __restrict__ cdec) {
  int idx = blockIdx.x * 256 + threadIdx.x;  // 4096*1536
  int m = idx / 1536, c = idx - m * 1536;
  if (c < 512) {
    Abuf[idx] = (bf16)0.f;
  } else {
    int j = c - 512;
    size_t s = (size_t)m * 1024 + j;
    Abuf[idx] = (bf16)h0[s];
    cdec[s] = c0[s];
  }
}

extern "C" void kernel_launch(void* const* d_in, const int* in_sizes, int n_in,
                              void* d_out, int out_size, void* d_ws, size_t ws_size,
                              hipStream_t stream) {
  const float* z        = (const float*)d_in[0];
  const float* dec_h0   = (const float*)d_in[1];
  const float* dec_c0   = (const float*)d_in[2];
  const float* cond_Wih = (const float*)d_in[5];
  const float* cond_Whh = (const float*)d_in[6];
  const float* cond_bih = (const float*)d_in[7];
  const float* cond_bhh = (const float*)d_in[8];
  const float* dec_Wih  = (const float*)d_in[9];
  const float* dec_Whh  = (const float*)d_in[10];
  const float* dec_bih  = (const float*)d_in[11];
  const float* dec_bhh  = (const float*)d_in[12];
  const float* out_W    = (const float*)d_in[13];
  const float* out_b    = (const float*)d_in[14];
  float* out = (float*)d_out;

  char* ws = (char*)d_ws;
  size_t off = 0;
  auto alloc = [&](size_t bytes) {
    void* p = ws + off;
    off += (bytes + 255) & ~(size_t)255;
    return p;
  };
  bf16* E    = (bf16*)alloc(4096ull * 4096 * 2);   // emb @ We^T, P layout, bf16
  bf16* Xz   = (bf16*)alloc(4096ull * 4096 * 2);   // z @ Wcih^T for all levels, P layout
  float* cdec = (float*)alloc(4096ull * 1024 * 4);
  bf16* Abuf  = (bf16*)alloc(4096ull * 1536 * 2);  // [note(512) | h(1024)] bf16
  bf16* Wd    = (bf16*)alloc(4096ull * 1536 * 2);  // P-packed [Wih_note | Whh]
  bf16* We    = (bf16*)alloc(4096ull * 1024 * 2);  // P-packed Wih_emb
  bf16* Wcih  = (bf16*)alloc(4096ull * 512 * 2);   // P-packed
  bf16* Wchh  = (bf16*)alloc(4096ull * 1024 * 2);  // P-packed
  bf16* Wo    = (bf16*)alloc(512ull * 1024 * 2);
  float* cc   = (float*)alloc(256ull * 1024 * 4);
  bf16* emb   = (bf16*)alloc(4096ull * 1024 * 2);  // conductor h per level (bf16)
  bf16* Zb    = (bf16*)alloc(4096ull * 512 * 2);
  bf16* hz0   = (bf16*)alloc(256ull * 1024 * 2);
  float* bdP  = (float*)alloc(4096ull * 4);
  float* bcP  = (float*)alloc(4096ull * 4);

  dim3 b256(256);

  // packing
  pack_w_perm<<<4096 * 512 / 256, b256, 0, stream>>>(cond_Wih, Wcih, 512);
  pack_w_perm<<<4096 * 1024 / 256, b256, 0, stream>>>(cond_Whh, Wchh, 1024);
  conv_f32_bf16<<<(512 * 1024 + 255) / 256, b256, 0, stream>>>(out_W, Wo, 512 * 1024);
  pack_w_dec<<<4096 * 1536 / 256, b256, 0, stream>>>(dec_Wih, dec_Whh, Wd);
  pack_w_emb<<<4096 * 1024 / 256, b256, 0, stream>>>(dec_Wih, We);
  pack_bias<<<16, b256, 0, stream>>>(dec_bih, dec_bhh, bdP);
  pack_bias<<<16, b256, 0, stream>>>(cond_bih, cond_bhh, bcP);
  pack_zb<<<4096 * 512 / 256, b256, 0, stream>>>(z, Zb);
  init_cond<<<256 * 1024 / 256, b256, 0, stream>>>(cc, hz0);
  init_state<<<4096 * 1536 / 256, b256, 0, stream>>>(dec_h0, dec_c0, Abuf, cdec);

  // Xz = Zb @ Wcih^T for all 16 levels at once (bf16, P layout)
  gemm_bt<128, 128, 2, 2, 2><<<dim3(32, 32), dim3(256), 0, stream>>>(
      Zb, 512, Wcih, 512, (float*)Xz, 4096, 512, nullptr, nullptr, nullptr, 0);

  // conductor chain: 16 sequential fused (h@Whh^T + Xz + bias -> cell) steps
  for (int l = 0; l < 16; ++l) {
    const bf16* hprev = (l == 0) ? hz0 : (emb + (size_t)(l - 1) * 256 * 1024);
    gemm_cell<32, 2, 2, 2><<<dim3(32, 8), dim3(256), 0, stream>>>(
        hprev, 1024, Wchh, Xz + (size_t)l * 256 * 4096, bcP,
        cc, emb + (size_t)l * 256 * 1024, 1024, 1024);
  }

  // E = emb @ We^T (bf16, P layout)
  gemm_bt<128, 128, 2, 2, 2><<<dim3(32, 32), dim3(256), 0, stream>>>(
      emb, 1024, We, 1024, (float*)E, 4096, 1024, nullptr, nullptr, nullptr, 0);

  // 16 autoregressive decoder steps (all 16 levels batched, M = 4096)
  for (int n = 0; n < 16; ++n) {
    gemm_cell<128, 4, 2, 2><<<dim3(16, 32), dim3(256), 0, stream>>>(
        Abuf, 1536, Wd, E, bdP, cdec, Abuf + 512, 1536, 1536);
    gemm_bt<128, 64, 2, 2, 1><<<dim3(512 / 64, 4096 / 128), dim3(256), 0, stream>>>(
        Abuf + 512, 1536, Wo, 1024, nullptr, 0, 1024, out_b, out, Abuf, n);
  }
}

// Round 3
// 1880.424 us; speedup vs baseline: 1.3011x; 1.0524x over previous
//
#include <hip/hip_runtime.h>

typedef __bf16 bf16;
typedef __attribute__((ext_vector_type(8))) __bf16 bf16x8;
typedef __attribute__((ext_vector_type(4))) float f32x4;

__device__ __forceinline__ void gload_lds16(const void* g, void* l) {
  __builtin_amdgcn_global_load_lds(
      (const __attribute__((address_space(1))) void*)g,
      (__attribute__((address_space(3))) void*)l, 16, 0, 0);
}

__device__ __forceinline__ float sigmoidf_(float x) { return 1.0f / (1.0f + expf(-x)); }

#define SB() __builtin_amdgcn_sched_barrier(0)
#define BAR()                          \
  do {                                 \
    SB();                              \
    __builtin_amdgcn_s_barrier();      \
    SB();                              \
  } while (0)

// ---------------------------------------------------------------------------
// 256x256-tile, 8-phase, counted-vmcnt GEMM over N=4096 P-packed weights.
//   A  [M x K] bf16 row-major (lda), Bw [4096 x K] bf16 (P-packed rows).
// MODE 0: bf16 store into Cb [M x 4096].
// MODE 1: fused LSTM cell: gates += X (bf16, P layout) + bias (f32, P layout);
//         c' = sig(f)*c + sig(i)*tanh(g); h = sig(o)*tanh(c') -> hout (ldh).
// LDS: 2 dbuf x (A 32KB + B 32KB) = 128 KiB (dynamic).
// st_16x32 swizzle: LDS loc (row, col8) holds element (row, col8 ^ ((row>>2&1)<<4));
// global_load_lds dest linear in tid, source pre-unswizzled (rule #21).
// ---------------------------------------------------------------------------
template<int MODE>
__global__ __launch_bounds__(512, 2)
void gemm8(const bf16* __restrict__ A, int lda,
           const bf16* __restrict__ Bw, int K,
           bf16* __restrict__ Cb,
           const bf16* __restrict__ X, const float* __restrict__ bias,
           float* __restrict__ cst, bf16* __restrict__ hout, int ldh) {
  extern __shared__ __align__(16) char smem_raw[];
  bf16* lsA = (bf16*)smem_raw;   // [2][16384]
  bf16* lsB = lsA + 2 * 16384;   // [2][16384]

  const int tid = threadIdx.x;
  const int lane = tid & 63;
  const int wave = tid >> 6;
  const int wm = wave >> 2, wn = wave & 3;

  // XCD-aware bijective swizzle (256 wgs, 16x16 tiles)
  const int bid = blockIdx.x;
  const int wgid = (bid & 7) * 32 + (bid >> 3);
  const int m0 = (wgid >> 4) * 256, n0 = (wgid & 15) * 256;

  const int nkt = K >> 6;

  // staging constants: dest linear in tid; source col pre-unswizzled
  const int srow = tid >> 3;  // 0..63
  const int csw = ((tid & 7) * 8) ^ (((tid >> 5) & 1) << 4);
  const bf16* gA = A + (size_t)m0 * lda + csw;
  const bf16* gB = Bw + (size_t)n0 * K + csw;

  auto stageA = [&](int c, int h, int kt) {
    bf16* d = lsA + c * 16384 + h * 8192 + tid * 8;
    const bf16* s = gA + (size_t)(h * 128 + srow) * lda + kt * 64;
    gload_lds16(s, d);
    gload_lds16(s + (size_t)64 * lda, d + 4096);
  };
  auto stageB = [&](int c, int h, int kt) {
    bf16* d = lsB + c * 16384 + h * 8192 + tid * 8;
    const bf16* s = gB + (size_t)(h * 128 + srow) * K + kt * 64;
    gload_lds16(s, d);
    gload_lds16(s + (size_t)64 * K, d + 4096);
  };

  // ds_read constants (elements); swizzle bit = row bit2 = lane bit2
  const int sw16 = ((lane >> 2) & 1) << 4;
  const int c0 = (((lane >> 4) * 8)) ^ sw16;       // ks=0
  const int c1 = (32 + ((lane >> 4) * 8)) ^ sw16;  // ks=1
  const int arow = (wm * 128 + (lane & 15)) * 64;
  const int brow = (wn * 64 + (lane & 15)) * 64;

  f32x4 acc[8][4] = {};

  // prologue: tile0 -> buf0, tile1 -> buf1 (16 loads), wait oldest 8
  stageA(0, 0, 0); stageA(0, 1, 0); stageB(0, 0, 0); stageB(0, 1, 0);
  if (nkt > 1) { stageA(1, 0, 1); stageA(1, 1, 1); stageB(1, 0, 1); stageB(1, 1, 1); }
  if (nkt > 1) asm volatile("s_waitcnt vmcnt(8)" ::: "memory");
  else         asm volatile("s_waitcnt vmcnt(0)" ::: "memory");
  BAR();

  for (int t = 0; t < nkt; ++t) {
    const int c = t & 1;
    const bf16* pA = lsA + c * 16384;
    const bf16* pB = lsB + c * 16384;
    const bool pre = (t + 2 < nkt);

    bf16x8 av[4][2], bv[4][2];

    // ---- Ph1: read A f0-3 + B g0-1; MFMA f0-3 x g0-1 ----
#pragma unroll
    for (int f = 0; f < 4; ++f) {
      av[f][0] = *(const bf16x8*)&pA[arow + f * 1024 + c0];
      av[f][1] = *(const bf16x8*)&pA[arow + f * 1024 + c1];
    }
#pragma unroll
    for (int g = 0; g < 2; ++g) {
      bv[g][0] = *(const bf16x8*)&pB[brow + g * 1024 + c0];
      bv[g][1] = *(const bf16x8*)&pB[brow + g * 1024 + c1];
    }
    BAR();
    __builtin_amdgcn_s_setprio(1);
#pragma unroll
    for (int f = 0; f < 4; ++f)
#pragma unroll
      for (int g = 0; g < 2; ++g) {
        acc[f][g] = __builtin_amdgcn_mfma_f32_16x16x32_bf16(av[f][0], bv[g][0], acc[f][g], 0, 0, 0);
        acc[f][g] = __builtin_amdgcn_mfma_f32_16x16x32_bf16(av[f][1], bv[g][1], acc[f][g], 0, 0, 0);
      }
    __builtin_amdgcn_s_setprio(0);
    BAR();

    // ---- Ph2: read B g2-3; MFMA f0-3 x g2-3 ----
#pragma unroll
    for (int g = 2; g < 4; ++g) {
      bv[g][0] = *(const bf16x8*)&pB[brow + g * 1024 + c0];
      bv[g][1] = *(const bf16x8*)&pB[brow + g * 1024 + c1];
    }
    BAR();
    __builtin_amdgcn_s_setprio(1);
#pragma unroll
    for (int f = 0; f < 4; ++f)
#pragma unroll
      for (int g = 2; g < 4; ++g) {
        acc[f][g] = __builtin_amdgcn_mfma_f32_16x16x32_bf16(av[f][0], bv[g][0], acc[f][g], 0, 0, 0);
        acc[f][g] = __builtin_amdgcn_mfma_f32_16x16x32_bf16(av[f][1], bv[g][1], acc[f][g], 0, 0, 0);
      }
    __builtin_amdgcn_s_setprio(0);
    BAR();

    // ---- Ph3: stage B(t+2) into buf c (B region fully consumed); read A f4-7;
    //           MFMA f4-7 x g0-1 ----
    if (pre) { stageB(c, 0, t + 2); stageB(c, 1, t + 2); }
#pragma unroll
    for (int f = 0; f < 4; ++f) {
      av[f][0] = *(const bf16x8*)&pA[arow + (f + 4) * 1024 + c0];
      av[f][1] = *(const bf16x8*)&pA[arow + (f + 4) * 1024 + c1];
    }
    BAR();
    __builtin_amdgcn_s_setprio(1);
#pragma unroll
    for (int f = 0; f < 4; ++f)
#pragma unroll
      for (int g = 0; g < 2; ++g) {
        acc[f + 4][g] = __builtin_amdgcn_mfma_f32_16x16x32_bf16(av[f][0], bv[g][0], acc[f + 4][g], 0, 0, 0);
        acc[f + 4][g] = __builtin_amdgcn_mfma_f32_16x16x32_bf16(av[f][1], bv[g][1], acc[f + 4][g], 0, 0, 0);
      }
    __builtin_amdgcn_s_setprio(0);
    BAR();

    // ---- Ph4: stage A(t+2) (A region fully consumed); MFMA f4-7 x g2-3;
    //           counted vmcnt; barrier ----
    if (pre) { stageA(c, 0, t + 2); stageA(c, 1, t + 2); }
    SB();
    __builtin_amdgcn_s_setprio(1);
#pragma unroll
    for (int f = 0; f < 4; ++f)
#pragma unroll
      for (int g = 2; g < 4; ++g) {
        acc[f + 4][g] = __builtin_amdgcn_mfma_f32_16x16x32_bf16(av[f][0], bv[g][0], acc[f + 4][g], 0, 0, 0);
        acc[f + 4][g] = __builtin_amdgcn_mfma_f32_16x16x32_bf16(av[f][1], bv[g][1], acc[f + 4][g], 0, 0, 0);
      }
    __builtin_amdgcn_s_setprio(0);
    if (pre) asm volatile("s_waitcnt vmcnt(8)" ::: "memory");
    else     asm volatile("s_waitcnt vmcnt(0)" ::: "memory");
    BAR();
  }

  // ---------------- epilogue ----------------
  const int jj = lane & 15;
  const int rb = m0 + wm * 128 + ((lane >> 4) << 2);
  if constexpr (MODE == 0) {
    const int col0 = n0 + wn * 64 + jj;
#pragma unroll
    for (int f = 0; f < 8; ++f)
#pragma unroll
      for (int g = 0; g < 4; ++g)
#pragma unroll
        for (int r = 0; r < 4; ++r)
          Cb[(size_t)(rb + f * 16 + r) * 4096 + col0 + g * 16] = (bf16)acc[f][g][r];
  } else {
    const int q = (n0 >> 6) + wn;  // j16 group (wave-uniform)
    const int j = q * 16 + jj;
    const float b0 = bias[q * 64 + jj];
    const float b1 = bias[q * 64 + 16 + jj];
    const float b2 = bias[q * 64 + 32 + jj];
    const float b3 = bias[q * 64 + 48 + jj];
#pragma unroll
    for (int f = 0; f < 8; ++f) {
#pragma unroll
      for (int r = 0; r < 4; ++r) {
        const int row = rb + f * 16 + r;
        const bf16* xp = X + (size_t)row * 4096 + q * 64 + jj;
        const float gi = acc[f][0][r] + (float)xp[0] + b0;
        const float gf = acc[f][1][r] + (float)xp[16] + b1;
        const float gg = acc[f][2][r] + (float)xp[32] + b2;
        const float go = acc[f][3][r] + (float)xp[48] + b3;
        const size_t ci = (size_t)row * 1024 + j;
        const float cn = sigmoidf_(gf) * cst[ci] + sigmoidf_(gi) * tanhf(gg);
        cst[ci] = cn;
        hout[(size_t)row * ldh + j] = (bf16)(sigmoidf_(go) * tanhf(cn));
      }
    }
  }
}

// ---------------------------------------------------------------------------
// 2-phase GEMM kept for the out-projection (N=512: 256-tile grid too small).
// MODE 1: sigmoid + scatter to notes + bf16 note feedback.
// ---------------------------------------------------------------------------
template<int BM, int BN, int WM, int WN, int MODE>
__global__ __launch_bounds__(WM * WN * 64)
void gemm_bt(const bf16* __restrict__ A, int lda,
             const bf16* __restrict__ Bw, int ldb,
             float* __restrict__ C, int ldc, int K,
             const float* __restrict__ outb, float* __restrict__ dout,
             bf16* __restrict__ anote, int nstep) {
  constexpr int BK = 64;
  constexpr int THREADS = WM * WN * 64;
  constexpr int SM = BM / WM, SN = BN / WN;
  constexpr int FM = SM / 16, FN = SN / 16;

  __shared__ __align__(16) bf16 lsA[BM * BK];
  __shared__ __align__(16) bf16 lsB[BN * BK];

  const int tid = threadIdx.x;
  const int lane = tid & 63;
  const int wave = tid >> 6;
  const int wm = wave / WN, wn = wave % WN;
  const int m0 = blockIdx.y * BM;
  const int n0 = blockIdx.x * BN;

  f32x4 acc[FM][FN] = {};

  const bf16* gA = A + (size_t)m0 * lda;
  const bf16* gB = Bw + (size_t)n0 * ldb;

  for (int k0 = 0; k0 < K; k0 += BK) {
#pragma unroll
    for (int i = 0; i < (BM * 8) / THREADS; ++i) {
      int idx = i * THREADS + tid;
      gload_lds16(gA + (size_t)(idx >> 3) * lda + k0 + (idx & 7) * 8, &lsA[idx * 8]);
    }
#pragma unroll
    for (int i = 0; i < (BN * 8) / THREADS; ++i) {
      int idx = i * THREADS + tid;
      gload_lds16(gB + (size_t)(idx >> 3) * ldb + k0 + (idx & 7) * 8, &lsB[idx * 8]);
    }
    __syncthreads();

#pragma unroll
    for (int kk = 0; kk < BK; kk += 32) {
      bf16x8 av[FM], bv[FN];
#pragma unroll
      for (int i = 0; i < FM; ++i)
        av[i] = *(const bf16x8*)&lsA[(wm * SM + i * 16 + (lane & 15)) * BK + kk + (lane >> 4) * 8];
#pragma unroll
      for (int j = 0; j < FN; ++j)
        bv[j] = *(const bf16x8*)&lsB[(wn * SN + j * 16 + (lane & 15)) * BK + kk + (lane >> 4) * 8];
#pragma unroll
      for (int i = 0; i < FM; ++i)
#pragma unroll
        for (int j = 0; j < FN; ++j)
          acc[i][j] = __builtin_amdgcn_mfma_f32_16x16x32_bf16(av[i], bv[j], acc[i][j], 0, 0, 0);
    }
    __syncthreads();
  }

#pragma unroll
  for (int i = 0; i < FM; ++i) {
#pragma unroll
    for (int j = 0; j < FN; ++j) {
      const int col = n0 + wn * SN + j * 16 + (lane & 15);
      const int rbase = m0 + wm * SM + i * 16 + ((lane >> 4) << 2);
#pragma unroll
      for (int r = 0; r < 4; ++r) {
        const int row = rbase + r;
        float v = acc[i][j][r];
        if constexpr (MODE == 0) {
          C[(size_t)row * ldc + col] = v;
        } else {
          v = sigmoidf_(v + outb[col]);
          const int l = row >> 8, b = row & 255;
          dout[((size_t)(b * 256 + l * 16 + nstep)) * 512 + col] = v;
          anote[(size_t)row * 1536 + col] = (bf16)v;
        }
      }
    }
  }
}

// ---------------------------------------------------------------------------
// Small fused GEMM+cell for the conductor chain (M=256).
// ---------------------------------------------------------------------------
template<int BM, int BJ, int WM, int WJ>
__global__ __launch_bounds__(WM * WJ * 64, 2)
void gemm_cell(const bf16* __restrict__ A, int lda,
               const bf16* __restrict__ Bw,
               const bf16* __restrict__ X,
               const float* __restrict__ bias,
               float* __restrict__ cst,
               bf16* __restrict__ hout, int ldh, int K) {
  constexpr int BK = 64;
  constexpr int THREADS = WM * WJ * 64;
  constexpr int BN = BJ * 64;
  constexpr int SM = BM / WM;
  constexpr int TJ = BJ / WJ;
  constexpr int FM = SM / 16;

  __shared__ __align__(16) bf16 lsA[BM * BK];
  __shared__ __align__(16) bf16 lsB[BN * BK];

  const int tid = threadIdx.x;
  const int lane = tid & 63;
  const int wave = tid >> 6;
  const int wm = wave / WJ, wj = wave % WJ;
  const int m0 = blockIdx.y * BM;
  const int qb = blockIdx.x * BJ;

  f32x4 acc[FM][TJ][4] = {};

  const bf16* gA = A + (size_t)m0 * lda;
  const bf16* gB = Bw + (size_t)(qb * 64) * K;

  for (int k0 = 0; k0 < K; k0 += BK) {
#pragma unroll
    for (int i = 0; i < (BM * 8) / THREADS; ++i) {
      int idx = i * THREADS + tid;
      gload_lds16(gA + (size_t)(idx >> 3) * lda + k0 + (idx & 7) * 8, &lsA[idx * 8]);
    }
#pragma unroll
    for (int i = 0; i < (BN * 8) / THREADS; ++i) {
      int idx = i * THREADS + tid;
      gload_lds16(gB + (size_t)(idx >> 3) * K + k0 + (idx & 7) * 8, &lsB[idx * 8]);
    }
    __syncthreads();

#pragma unroll
    for (int kk = 0; kk < BK; kk += 32) {
      bf16x8 av[FM], bv[TJ][4];
#pragma unroll
      for (int i = 0; i < FM; ++i)
        av[i] = *(const bf16x8*)&lsA[(wm * SM + i * 16 + (lane & 15)) * BK + kk + (lane >> 4) * 8];
#pragma unroll
      for (int t = 0; t < TJ; ++t)
#pragma unroll
        for (int g = 0; g < 4; ++g)
          bv[t][g] = *(const bf16x8*)
              &lsB[((wj * TJ + t) * 64 + g * 16 + (lane & 15)) * BK + kk + (lane >> 4) * 8];
#pragma unroll
      for (int i = 0; i < FM; ++i)
#pragma unroll
        for (int t = 0; t < TJ; ++t)
#pragma unroll
          for (int g = 0; g < 4; ++g)
            acc[i][t][g] =
                __builtin_amdgcn_mfma_f32_16x16x32_bf16(av[i], bv[t][g], acc[i][t][g], 0, 0, 0);
    }
    __syncthreads();
  }

#pragma unroll
  for (int i = 0; i < FM; ++i) {
#pragma unroll
    for (int t = 0; t < TJ; ++t) {
      const int q = qb + wj * TJ + t;
      const int jj = lane & 15;
      const int j = q * 16 + jj;
      const int rbase = m0 + wm * SM + i * 16 + ((lane >> 4) << 2);
      const float b0 = bias[q * 64 + jj];
      const float b1 = bias[q * 64 + 16 + jj];
      const float b2 = bias[q * 64 + 32 + jj];
      const float b3 = bias[q * 64 + 48 + jj];
#pragma unroll
      for (int r = 0; r < 4; ++r) {
        const int row = rbase + r;
        const bf16* xp = X + (size_t)row * 4096 + q * 64 + jj;
        const float gi = acc[i][t][0][r] + (float)xp[0] + b0;
        const float gf = acc[i][t][1][r] + (float)xp[16] + b1;
        const float gg = acc[i][t][2][r] + (float)xp[32] + b2;
        const float go = acc[i][t][3][r] + (float)xp[48] + b3;
        const size_t ci = (size_t)row * 1024 + j;
        const float c = sigmoidf_(gf) * cst[ci] + sigmoidf_(gi) * tanhf(gg);
        cst[ci] = c;
        hout[(size_t)row * ldh + j] = (bf16)(sigmoidf_(go) * tanhf(c));
      }
    }
  }
}

// ---------------- packing / init kernels ----------------

__global__ void conv_f32_bf16(const float* __restrict__ src, bf16* __restrict__ dst, int n) {
  int idx = blockIdx.x * 256 + threadIdx.x;
  if (idx < n) dst[idx] = (bf16)src[idx];
}

__device__ __forceinline__ int p_src_row(int n) {
  int q = n >> 6, gate = (n >> 4) & 3, jj = n & 15;
  return gate * 1024 + q * 16 + jj;
}

__global__ void pack_w_dec(const float* __restrict__ wih, const float* __restrict__ whh,
                           bf16* __restrict__ dst) {
  int idx = blockIdx.x * 256 + threadIdx.x;  // 4096*1536
  int n = idx / 1536, c = idx - n * 1536;
  int r = p_src_row(n);
  float v = (c < 512) ? wih[(size_t)r * 1536 + 1024 + c] : whh[(size_t)r * 1024 + (c - 512)];
  dst[idx] = (bf16)v;
}

__global__ void pack_w_emb(const float* __restrict__ wih, bf16* __restrict__ dst) {
  int idx = blockIdx.x * 256 + threadIdx.x;  // 4096*1024
  int n = idx >> 10, c = idx & 1023;
  dst[idx] = (bf16)wih[(size_t)p_src_row(n) * 1536 + c];
}

__global__ void pack_w_perm(const float* __restrict__ src, bf16* __restrict__ dst, int Kw) {
  int idx = blockIdx.x * 256 + threadIdx.x;  // 4096*Kw
  int n = idx / Kw, c = idx - n * Kw;
  dst[idx] = (bf16)src[(size_t)p_src_row(n) * Kw + c];
}

__global__ void pack_bias(const float* __restrict__ bih, const float* __restrict__ bhh,
                          float* __restrict__ dst) {
  int n = blockIdx.x * 256 + threadIdx.x;  // 4096
  int r = p_src_row(n);
  dst[n] = bih[r] + bhh[r];
}

__global__ void pack_zb(const float* __restrict__ z, bf16* __restrict__ dst) {
  int idx = blockIdx.x * 256 + threadIdx.x;  // 4096*512
  int m = idx >> 9, k = idx & 511;
  int l = m >> 8, b = m & 255;
  dst[idx] = (bf16)z[((size_t)b * 256 + 16 * l) * 512 + k];
}

__global__ void init_cond(float* __restrict__ cc, bf16* __restrict__ hz0) {
  int idx = blockIdx.x * 256 + threadIdx.x;  // 256*1024
  cc[idx] = 0.f;
  hz0[idx] = (bf16)0.f;
}

__global__ void init_state(const float* __restrict__ h0, const float* __restrict__ c0,
                           bf16* __restrict__ Abuf, float* __restrict__ cdec) {
  int idx = blockIdx.x * 256 + threadIdx.x;  // 4096*1536
  int m = idx / 1536, c = idx - m * 1536;
  if (c < 512) {
    Abuf[idx] = (bf16)0.f;
  } else {
    int j = c - 512;
    size_t s = (size_t)m * 1024 + j;
    Abuf[idx] = (bf16)h0[s];
    cdec[s] = c0[s];
  }
}

extern "C" void kernel_launch(void* const* d_in, const int* in_sizes, int n_in,
                              void* d_out, int out_size, void* d_ws, size_t ws_size,
                              hipStream_t stream) {
  const float* z        = (const float*)d_in[0];
  const float* dec_h0   = (const float*)d_in[1];
  const float* dec_c0   = (const float*)d_in[2];
  const float* cond_Wih = (const float*)d_in[5];
  const float* cond_Whh = (const float*)d_in[6];
  const float* cond_bih = (const float*)d_in[7];
  const float* cond_bhh = (const float*)d_in[8];
  const float* dec_Wih  = (const float*)d_in[9];
  const float* dec_Whh  = (const float*)d_in[10];
  const float* dec_bih  = (const float*)d_in[11];
  const float* dec_bhh  = (const float*)d_in[12];
  const float* out_W    = (const float*)d_in[13];
  const float* out_b    = (const float*)d_in[14];
  float* out = (float*)d_out;

  char* ws = (char*)d_ws;
  size_t off = 0;
  auto alloc = [&](size_t bytes) {
    void* p = ws + off;
    off += (bytes + 255) & ~(size_t)255;
    return p;
  };
  bf16* E     = (bf16*)alloc(4096ull * 4096 * 2);   // emb @ We^T, P layout
  bf16* Xz    = (bf16*)alloc(4096ull * 4096 * 2);   // z @ Wcih^T, P layout
  float* cdec = (float*)alloc(4096ull * 1024 * 4);
  bf16* Abuf  = (bf16*)alloc(4096ull * 1536 * 2);   // [note(512) | h(1024)]
  bf16* Wd    = (bf16*)alloc(4096ull * 1536 * 2);   // P-packed [Wih_note | Whh]
  bf16* We    = (bf16*)alloc(4096ull * 1024 * 2);   // P-packed Wih_emb
  bf16* Wcih  = (bf16*)alloc(4096ull * 512 * 2);    // P-packed
  bf16* Wchh  = (bf16*)alloc(4096ull * 1024 * 2);   // P-packed
  bf16* Wo    = (bf16*)alloc(512ull * 1024 * 2);
  float* cc   = (float*)alloc(256ull * 1024 * 4);
  bf16* emb   = (bf16*)alloc(4096ull * 1024 * 2);
  bf16* Zb    = (bf16*)alloc(4096ull * 512 * 2);
  bf16* hz0   = (bf16*)alloc(256ull * 1024 * 2);
  float* bdP  = (float*)alloc(4096ull * 4);
  float* bcP  = (float*)alloc(4096ull * 4);

  dim3 b256(256);

  // allow 128 KiB dynamic LDS for the 8-phase kernels (idempotent)
  hipFuncSetAttribute(reinterpret_cast<const void*>(&gemm8<0>),
                      hipFuncAttributeMaxDynamicSharedMemorySize, 131072);
  hipFuncSetAttribute(reinterpret_cast<const void*>(&gemm8<1>),
                      hipFuncAttributeMaxDynamicSharedMemorySize, 131072);

  // packing
  pack_w_perm<<<4096 * 512 / 256, b256, 0, stream>>>(cond_Wih, Wcih, 512);
  pack_w_perm<<<4096 * 1024 / 256, b256, 0, stream>>>(cond_Whh, Wchh, 1024);
  conv_f32_bf16<<<(512 * 1024 + 255) / 256, b256, 0, stream>>>(out_W, Wo, 512 * 1024);
  pack_w_dec<<<4096 * 1536 / 256, b256, 0, stream>>>(dec_Wih, dec_Whh, Wd);
  pack_w_emb<<<4096 * 1024 / 256, b256, 0, stream>>>(dec_Wih, We);
  pack_bias<<<16, b256, 0, stream>>>(dec_bih, dec_bhh, bdP);
  pack_bias<<<16, b256, 0, stream>>>(cond_bih, cond_bhh, bcP);
  pack_zb<<<4096 * 512 / 256, b256, 0, stream>>>(z, Zb);
  init_cond<<<256 * 1024 / 256, b256, 0, stream>>>(cc, hz0);
  init_state<<<4096 * 1536 / 256, b256, 0, stream>>>(dec_h0, dec_c0, Abuf, cdec);

  // Xz = Zb @ Wcih^T (bf16, P layout), 8-phase
  gemm8<0><<<256, 512, 131072, stream>>>(Zb, 512, Wcih, 512, Xz,
                                         nullptr, nullptr, nullptr, nullptr, 0);

  // conductor chain: 16 sequential fused steps (M=256, small kernel)
  for (int l = 0; l < 16; ++l) {
    const bf16* hprev = (l == 0) ? hz0 : (emb + (size_t)(l - 1) * 256 * 1024);
    gemm_cell<32, 2, 2, 2><<<dim3(32, 8), dim3(256), 0, stream>>>(
        hprev, 1024, Wchh, Xz + (size_t)l * 256 * 4096, bcP,
        cc, emb + (size_t)l * 256 * 1024, 1024, 1024);
  }

  // E = emb @ We^T (bf16, P layout), 8-phase
  gemm8<0><<<256, 512, 131072, stream>>>(emb, 1024, We, 1024, E,
                                         nullptr, nullptr, nullptr, nullptr, 0);

  // 16 autoregressive decoder steps (M = 4096), fused 8-phase GEMM+cell
  for (int n = 0; n < 16; ++n) {
    gemm8<1><<<256, 512, 131072, stream>>>(Abuf, 1536, Wd, 1536, nullptr,
                                           E, bdP, cdec, Abuf + 512, 1536);
    gemm_bt<128, 64, 2, 2, 1><<<dim3(512 / 64, 4096 / 128), dim3(256), 0, stream>>>(
        Abuf + 512, 1536, Wo, 1024, nullptr, 0, 1024, out_b, out, Abuf, n);
  }
}

// Round 4
// 1750.152 us; speedup vs baseline: 1.3979x; 1.0744x over previous
//
#include <hip/hip_runtime.h>

typedef __bf16 bf16;
typedef __attribute__((ext_vector_type(8))) __bf16 bf16x8;
typedef __attribute__((ext_vector_type(4))) float f32x4;
typedef __attribute__((ext_vector_type(4))) unsigned short u16x4;

__device__ __forceinline__ void gload_lds16(const void* g, void* l) {
  __builtin_amdgcn_global_load_lds(
      (const __attribute__((address_space(1))) void*)g,
      (__attribute__((address_space(3))) void*)l, 16, 0, 0);
}

__device__ __forceinline__ float sigmoidf_(float x) { return 1.0f / (1.0f + expf(-x)); }

__device__ __forceinline__ float bf2f(unsigned short u) {
  union { unsigned int i; float f; } v;
  v.i = ((unsigned int)u) << 16;
  return v.f;
}
__device__ __forceinline__ unsigned short f2bfbits(float x) {
  union { bf16 b; unsigned short u; } v;
  v.b = (bf16)x;
  return v.u;
}

#define SB() __builtin_amdgcn_sched_barrier(0)
#define BAR()                          \
  do {                                 \
    SB();                              \
    __builtin_amdgcn_s_barrier();      \
    SB();                              \
  } while (0)

#define MFMA16(a, b, c) __builtin_amdgcn_mfma_f32_16x16x32_bf16(a, b, c, 0, 0, 0)

// ---------------------------------------------------------------------------
// 256x256-tile, 4-phase/K-tile, counted-vmcnt, shadow-pipelined ds_read GEMM
// over N=4096 P-packed weights. A [M x K] bf16 (lda), Bw [4096 x K] bf16.
// 3-bit XOR swizzle: LDS (row, slot8) holds element (row, slot8 ^ (row&7));
// staging source pre-unswizzled, ds_read applies the same XOR (rule #21).
// MODE 0: pack 4 gates -> u16x4 store into Cb [M x 4096] gate-interleaved
//         layout (q*64 + jj*4 + g).
// MODE 1: fused LSTM cell; X (bf16) and bias (f32) in gate-interleaved layout;
//         c' = sig(f)*c + sig(i)*tanh(g); h = sig(o)*tanh(c') -> hout (ldh).
// ---------------------------------------------------------------------------
template<int MODE>
__global__ __launch_bounds__(512, 2)
void gemm8(const bf16* __restrict__ A, int lda,
           const bf16* __restrict__ Bw, int K,
           bf16* __restrict__ Cb,
           const bf16* __restrict__ X, const float* __restrict__ bias,
           float* __restrict__ cst, bf16* __restrict__ hout, int ldh) {
  extern __shared__ __align__(16) char smem_raw[];
  bf16* lsA = (bf16*)smem_raw;   // [2][16384]
  bf16* lsB = lsA + 2 * 16384;   // [2][16384]

  const int tid = threadIdx.x;
  const int lane = tid & 63;
  const int wave = tid >> 6;
  const int wm = wave >> 2, wn = wave & 3;

  const int bid = blockIdx.x;
  const int wgid = (bid & 7) * 32 + (bid >> 3);  // XCD-bijective (256 wgs)
  const int m0 = (wgid >> 4) * 256, n0 = (wgid & 15) * 256;

  const int nkt = K >> 6;

  // staging: dest linear in tid; source col pre-unswizzled (3-bit XOR)
  const int srow = tid >> 3;
  const int csw = ((tid & 7) * 8) ^ ((srow & 7) << 3);
  const bf16* gA = A + (size_t)m0 * lda + csw;
  const bf16* gB = Bw + (size_t)n0 * K + csw;

  auto stageA = [&](int kt) {
    bf16* d = lsA + (kt & 1) * 16384 + tid * 8;
    const bf16* s = gA + (size_t)srow * lda + (size_t)kt * 64;
    gload_lds16(s, d);
    gload_lds16(s + (size_t)64 * lda, d + 4096);
    gload_lds16(s + (size_t)128 * lda, d + 8192);
    gload_lds16(s + (size_t)192 * lda, d + 12288);
  };
  auto stageB = [&](int kt) {
    bf16* d = lsB + (kt & 1) * 16384 + tid * 8;
    const bf16* s = gB + (size_t)srow * K + (size_t)kt * 64;
    gload_lds16(s, d);
    gload_lds16(s + (size_t)64 * K, d + 4096);
    gload_lds16(s + (size_t)128 * K, d + 8192);
    gload_lds16(s + (size_t)192 * K, d + 12288);
  };

  // ds_read columns: 3-bit swizzle, conflict-free
  const int c0 = ((lane >> 4) * 8) ^ ((lane & 7) << 3);
  const int c1 = c0 ^ 32;
  const int abase = (wm * 128 + (lane & 15)) * 64;
  const int bbase = (wn * 64 + (lane & 15)) * 64;

  f32x4 acc[8][4] = {};

  // prologue: tile0 (A+B) + B1; wait tile0 (leave B1's 4 loads in flight)
  stageA(0); stageB(0);
  if (nkt > 1) stageB(1);
  if (nkt > 1) asm volatile("s_waitcnt vmcnt(4)" ::: "memory");
  else         asm volatile("s_waitcnt vmcnt(0)" ::: "memory");
  BAR();

  for (int u = 0; u < nkt; ++u) {
    const int c = u & 1;
    const bf16* pA = lsA + c * 16384;
    const bf16* pB = lsB + c * 16384;
    bf16x8 avA[4], avB[4], avC[4], avD[4], bvA[4], bvB[4];

    // ---- Ph1: stage A(u+1); read {A f0-3 ks0, B ks0} + shadow {A f4-7 ks0};
    //           MFMA f0-3 x g0-3 ks0 ----
    if (u + 1 < nkt) stageA(u + 1);
#pragma unroll
    for (int f = 0; f < 4; ++f) avA[f] = *(const bf16x8*)&pA[abase + f * 1024 + c0];
#pragma unroll
    for (int g = 0; g < 4; ++g) bvA[g] = *(const bf16x8*)&pB[bbase + g * 1024 + c0];
#pragma unroll
    for (int f = 0; f < 4; ++f) avB[f] = *(const bf16x8*)&pA[abase + (f + 4) * 1024 + c0];
    BAR();
    __builtin_amdgcn_s_setprio(1);
#pragma unroll
    for (int f = 0; f < 4; ++f)
#pragma unroll
      for (int g = 0; g < 4; ++g)
        acc[f][g] = MFMA16(avA[f], bvA[g], acc[f][g]);
    __builtin_amdgcn_s_setprio(0);
    BAR();

    // ---- Ph2: shadow-read {A f0-3 ks1, B ks1}; MFMA f4-7 x g0-3 ks0 ----
#pragma unroll
    for (int f = 0; f < 4; ++f) avC[f] = *(const bf16x8*)&pA[abase + f * 1024 + c1];
#pragma unroll
    for (int g = 0; g < 4; ++g) bvB[g] = *(const bf16x8*)&pB[bbase + g * 1024 + c1];
    __builtin_amdgcn_s_setprio(1);
#pragma unroll
    for (int f = 0; f < 4; ++f)
#pragma unroll
      for (int g = 0; g < 4; ++g)
        acc[f + 4][g] = MFMA16(avB[f], bvA[g], acc[f + 4][g]);
    __builtin_amdgcn_s_setprio(0);
    BAR();

    // ---- Ph3: shadow-read {A f4-7 ks1}; MFMA f0-3 x g0-3 ks1 ----
#pragma unroll
    for (int f = 0; f < 4; ++f) avD[f] = *(const bf16x8*)&pA[abase + (f + 4) * 1024 + c1];
    __builtin_amdgcn_s_setprio(1);
#pragma unroll
    for (int f = 0; f < 4; ++f)
#pragma unroll
      for (int g = 0; g < 4; ++g)
        acc[f][g] = MFMA16(avC[f], bvB[g], acc[f][g]);
    __builtin_amdgcn_s_setprio(0);
    BAR();

    // ---- Ph4: stage B(u+2) (B fully consumed after Ph3-end barrier);
    //           MFMA f4-7 x g0-3 ks1; counted vmcnt; barrier ----
    if (u + 2 < nkt) stageB(u + 2);
    SB();
    __builtin_amdgcn_s_setprio(1);
#pragma unroll
    for (int f = 0; f < 4; ++f)
#pragma unroll
      for (int g = 0; g < 4; ++g)
        acc[f + 4][g] = MFMA16(avD[f], bvB[g], acc[f + 4][g]);
    __builtin_amdgcn_s_setprio(0);
    if (u + 2 < nkt)      asm volatile("s_waitcnt vmcnt(4)" ::: "memory");
    else if (u + 1 < nkt) asm volatile("s_waitcnt vmcnt(0)" ::: "memory");
    BAR();
  }

  // ---------------- epilogue ----------------
  const int jj = lane & 15;
  const int rb = m0 + wm * 128 + ((lane >> 4) << 2);
  const int q = (n0 >> 6) + wn;  // j16 group (wave-uniform)
  if constexpr (MODE == 0) {
#pragma unroll
    for (int f = 0; f < 8; ++f)
#pragma unroll
      for (int r = 0; r < 4; ++r) {
        u16x4 pk;
        pk[0] = f2bfbits(acc[f][0][r]);
        pk[1] = f2bfbits(acc[f][1][r]);
        pk[2] = f2bfbits(acc[f][2][r]);
        pk[3] = f2bfbits(acc[f][3][r]);
        *(u16x4*)&Cb[(size_t)(rb + f * 16 + r) * 4096 + q * 64 + jj * 4] = pk;
      }
  } else {
    const int j = q * 16 + jj;
    const f32x4 bq = *(const f32x4*)&bias[q * 64 + jj * 4];
#pragma unroll
    for (int f = 0; f < 8; ++f) {
#pragma unroll
      for (int r = 0; r < 4; ++r) {
        const int row = rb + f * 16 + r;
        const u16x4 xv = *(const u16x4*)&X[(size_t)row * 4096 + q * 64 + jj * 4];
        const float gi = acc[f][0][r] + bf2f(xv[0]) + bq[0];
        const float gf = acc[f][1][r] + bf2f(xv[1]) + bq[1];
        const float gg = acc[f][2][r] + bf2f(xv[2]) + bq[2];
        const float go = acc[f][3][r] + bf2f(xv[3]) + bq[3];
        const size_t ci = (size_t)row * 1024 + j;
        const float cn = sigmoidf_(gf) * cst[ci] + sigmoidf_(gi) * tanhf(gg);
        cst[ci] = cn;
        hout[(size_t)row * ldh + j] = (bf16)(sigmoidf_(go) * tanhf(cn));
      }
    }
  }
}

// ---------------------------------------------------------------------------
// 2-phase GEMM kept for the out-projection (N=512).
// MODE 1: sigmoid + scatter to notes + bf16 note feedback.
// ---------------------------------------------------------------------------
template<int BM, int BN, int WM, int WN, int MODE>
__global__ __launch_bounds__(WM * WN * 64)
void gemm_bt(const bf16* __restrict__ A, int lda,
             const bf16* __restrict__ Bw, int ldb,
             float* __restrict__ C, int ldc, int K,
             const float* __restrict__ outb, float* __restrict__ dout,
             bf16* __restrict__ anote, int nstep) {
  constexpr int BK = 64;
  constexpr int THREADS = WM * WN * 64;
  constexpr int SM = BM / WM, SN = BN / WN;
  constexpr int FM = SM / 16, FN = SN / 16;

  __shared__ __align__(16) bf16 lsA[BM * BK];
  __shared__ __align__(16) bf16 lsB[BN * BK];

  const int tid = threadIdx.x;
  const int lane = tid & 63;
  const int wave = tid >> 6;
  const int wm = wave / WN, wn = wave % WN;
  const int m0 = blockIdx.y * BM;
  const int n0 = blockIdx.x * BN;

  f32x4 acc[FM][FN] = {};

  const bf16* gA = A + (size_t)m0 * lda;
  const bf16* gB = Bw + (size_t)n0 * ldb;

  for (int k0 = 0; k0 < K; k0 += BK) {
#pragma unroll
    for (int i = 0; i < (BM * 8) / THREADS; ++i) {
      int idx = i * THREADS + tid;
      gload_lds16(gA + (size_t)(idx >> 3) * lda + k0 + (idx & 7) * 8, &lsA[idx * 8]);
    }
#pragma unroll
    for (int i = 0; i < (BN * 8) / THREADS; ++i) {
      int idx = i * THREADS + tid;
      gload_lds16(gB + (size_t)(idx >> 3) * ldb + k0 + (idx & 7) * 8, &lsB[idx * 8]);
    }
    __syncthreads();

#pragma unroll
    for (int kk = 0; kk < BK; kk += 32) {
      bf16x8 av[FM], bv[FN];
#pragma unroll
      for (int i = 0; i < FM; ++i)
        av[i] = *(const bf16x8*)&lsA[(wm * SM + i * 16 + (lane & 15)) * BK + kk + (lane >> 4) * 8];
#pragma unroll
      for (int j = 0; j < FN; ++j)
        bv[j] = *(const bf16x8*)&lsB[(wn * SN + j * 16 + (lane & 15)) * BK + kk + (lane >> 4) * 8];
#pragma unroll
      for (int i = 0; i < FM; ++i)
#pragma unroll
        for (int j = 0; j < FN; ++j)
          acc[i][j] = MFMA16(av[i], bv[j], acc[i][j]);
    }
    __syncthreads();
  }

#pragma unroll
  for (int i = 0; i < FM; ++i) {
#pragma unroll
    for (int j = 0; j < FN; ++j) {
      const int col = n0 + wn * SN + j * 16 + (lane & 15);
      const int rbase = m0 + wm * SM + i * 16 + ((lane >> 4) << 2);
#pragma unroll
      for (int r = 0; r < 4; ++r) {
        const int row = rbase + r;
        float v = acc[i][j][r];
        if constexpr (MODE == 0) {
          C[(size_t)row * ldc + col] = v;
        } else {
          v = sigmoidf_(v + outb[col]);
          const int l = row >> 8, b = row & 255;
          dout[((size_t)(b * 256 + l * 16 + nstep)) * 512 + col] = v;
          anote[(size_t)row * 1536 + col] = (bf16)v;
        }
      }
    }
  }
}

// ---------------------------------------------------------------------------
// Small fused GEMM+cell for the conductor chain (M=256).
// X and bias in gate-interleaved layout (q*64 + jj*4 + g).
// ---------------------------------------------------------------------------
template<int BM, int BJ, int WM, int WJ>
__global__ __launch_bounds__(WM * WJ * 64, 2)
void gemm_cell(const bf16* __restrict__ A, int lda,
               const bf16* __restrict__ Bw,
               const bf16* __restrict__ X,
               const float* __restrict__ bias,
               float* __restrict__ cst,
               bf16* __restrict__ hout, int ldh, int K) {
  constexpr int BK = 64;
  constexpr int THREADS = WM * WJ * 64;
  constexpr int BN = BJ * 64;
  constexpr int SM = BM / WM;
  constexpr int TJ = BJ / WJ;
  constexpr int FM = SM / 16;

  __shared__ __align__(16) bf16 lsA[BM * BK];
  __shared__ __align__(16) bf16 lsB[BN * BK];

  const int tid = threadIdx.x;
  const int lane = tid & 63;
  const int wave = tid >> 6;
  const int wm = wave / WJ, wj = wave % WJ;
  const int m0 = blockIdx.y * BM;
  const int qb = blockIdx.x * BJ;

  f32x4 acc[FM][TJ][4] = {};

  const bf16* gA = A + (size_t)m0 * lda;
  const bf16* gB = Bw + (size_t)(qb * 64) * K;

  for (int k0 = 0; k0 < K; k0 += BK) {
#pragma unroll
    for (int i = 0; i < (BM * 8) / THREADS; ++i) {
      int idx = i * THREADS + tid;
      gload_lds16(gA + (size_t)(idx >> 3) * lda + k0 + (idx & 7) * 8, &lsA[idx * 8]);
    }
#pragma unroll
    for (int i = 0; i < (BN * 8) / THREADS; ++i) {
      int idx = i * THREADS + tid;
      gload_lds16(gB + (size_t)(idx >> 3) * K + k0 + (idx & 7) * 8, &lsB[idx * 8]);
    }
    __syncthreads();

#pragma unroll
    for (int kk = 0; kk < BK; kk += 32) {
      bf16x8 av[FM], bv[TJ][4];
#pragma unroll
      for (int i = 0; i < FM; ++i)
        av[i] = *(const bf16x8*)&lsA[(wm * SM + i * 16 + (lane & 15)) * BK + kk + (lane >> 4) * 8];
#pragma unroll
      for (int t = 0; t < TJ; ++t)
#pragma unroll
        for (int g = 0; g < 4; ++g)
          bv[t][g] = *(const bf16x8*)
              &lsB[((wj * TJ + t) * 64 + g * 16 + (lane & 15)) * BK + kk + (lane >> 4) * 8];
#pragma unroll
      for (int i = 0; i < FM; ++i)
#pragma unroll
        for (int t = 0; t < TJ; ++t)
#pragma unroll
          for (int g = 0; g < 4; ++g)
            acc[i][t][g] = MFMA16(av[i], bv[t][g], acc[i][t][g]);
    }
    __syncthreads();
  }

#pragma unroll
  for (int i = 0; i < FM; ++i) {
#pragma unroll
    for (int t = 0; t < TJ; ++t) {
      const int q = qb + wj * TJ + t;
      const int jj = lane & 15;
      const int j = q * 16 + jj;
      const int rbase = m0 + wm * SM + i * 16 + ((lane >> 4) << 2);
      const f32x4 bq = *(const f32x4*)&bias[q * 64 + jj * 4];
#pragma unroll
      for (int r = 0; r < 4; ++r) {
        const int row = rbase + r;
        const u16x4 xv = *(const u16x4*)&X[(size_t)row * 4096 + q * 64 + jj * 4];
        const float gi = acc[i][t][0][r] + bf2f(xv[0]) + bq[0];
        const float gf = acc[i][t][1][r] + bf2f(xv[1]) + bq[1];
        const float gg = acc[i][t][2][r] + bf2f(xv[2]) + bq[2];
        const float go = acc[i][t][3][r] + bf2f(xv[3]) + bq[3];
        const size_t ci = (size_t)row * 1024 + j;
        const float c = sigmoidf_(gf) * cst[ci] + sigmoidf_(gi) * tanhf(gg);
        cst[ci] = c;
        hout[(size_t)row * ldh + j] = (bf16)(sigmoidf_(go) * tanhf(c));
      }
    }
  }
}

// ---------------- packing / init kernels ----------------

__global__ void conv_f32_bf16(const float* __restrict__ src, bf16* __restrict__ dst, int n) {
  int idx = blockIdx.x * 256 + threadIdx.x;
  if (idx < n) dst[idx] = (bf16)src[idx];
}

// P-permuted row index: n' -> source row r = gate*1024 + q*16 + jj
__device__ __forceinline__ int p_src_row(int n) {
  int q = n >> 6, gate = (n >> 4) & 3, jj = n & 15;
  return gate * 1024 + q * 16 + jj;
}

__global__ void pack_w_dec(const float* __restrict__ wih, const float* __restrict__ whh,
                           bf16* __restrict__ dst) {
  int idx = blockIdx.x * 256 + threadIdx.x;  // 4096*1536
  int n = idx / 1536, c = idx - n * 1536;
  int r = p_src_row(n);
  float v = (c < 512) ? wih[(size_t)r * 1536 + 1024 + c] : whh[(size_t)r * 1024 + (c - 512)];
  dst[idx] = (bf16)v;
}

__global__ void pack_w_emb(const float* __restrict__ wih, bf16* __restrict__ dst) {
  int idx = blockIdx.x * 256 + threadIdx.x;  // 4096*1024
  int n = idx >> 10, c = idx & 1023;
  dst[idx] = (bf16)wih[(size_t)p_src_row(n) * 1536 + c];
}

__global__ void pack_w_perm(const float* __restrict__ src, bf16* __restrict__ dst, int Kw) {
  int idx = blockIdx.x * 256 + threadIdx.x;  // 4096*Kw
  int n = idx / Kw, c = idx - n * Kw;
  dst[idx] = (bf16)src[(size_t)p_src_row(n) * Kw + c];
}

// gate-interleaved bias: dst[q*64 + jj*4 + g] = bih[r] + bhh[r]
__global__ void pack_bias(const float* __restrict__ bih, const float* __restrict__ bhh,
                          float* __restrict__ dst) {
  int n = blockIdx.x * 256 + threadIdx.x;  // 4096
  int q = n >> 6, jj = (n >> 2) & 15, g = n & 3;
  int r = g * 1024 + q * 16 + jj;
  dst[n] = bih[r] + bhh[r];
}

__global__ void pack_zb(const float* __restrict__ z, bf16* __restrict__ dst) {
  int idx = blockIdx.x * 256 + threadIdx.x;  // 4096*512
  int m = idx >> 9, k = idx & 511;
  int l = m >> 8, b = m & 255;
  dst[idx] = (bf16)z[((size_t)b * 256 + 16 * l) * 512 + k];
}

__global__ void init_cond(float* __restrict__ cc, bf16* __restrict__ hz0) {
  int idx = blockIdx.x * 256 + threadIdx.x;  // 256*1024
  cc[idx] = 0.f;
  hz0[idx] = (bf16)0.f;
}

__global__ void init_state(const float* __restrict__ h0, const float* __restrict__ c0,
                           bf16* __restrict__ Abuf, float* __restrict__ cdec) {
  int idx = blockIdx.x * 256 + threadIdx.x;  // 4096*1536
  int m = idx / 1536, c = idx - m * 1536;
  if (c < 512) {
    Abuf[idx] = (bf16)0.f;
  } else {
    int j = c - 512;
    size_t s = (size_t)m * 1024 + j;
    Abuf[idx] = (bf16)h0[s];
    cdec[s] = c0[s];
  }
}

extern "C" void kernel_launch(void* const* d_in, const int* in_sizes, int n_in,
                              void* d_out, int out_size, void* d_ws, size_t ws_size,
                              hipStream_t stream) {
  const float* z        = (const float*)d_in[0];
  const float* dec_h0   = (const float*)d_in[1];
  const float* dec_c0   = (const float*)d_in[2];
  const float* cond_Wih = (const float*)d_in[5];
  const float* cond_Whh = (const float*)d_in[6];
  const float* cond_bih = (const float*)d_in[7];
  const float* cond_bhh = (const float*)d_in[8];
  const float* dec_Wih  = (const float*)d_in[9];
  const float* dec_Whh  = (const float*)d_in[10];
  const float* dec_bih  = (const float*)d_in[11];
  const float* dec_bhh  = (const float*)d_in[12];
  const float* out_W    = (const float*)d_in[13];
  const float* out_b    = (const float*)d_in[14];
  float* out = (float*)d_out;

  char* ws = (char*)d_ws;
  size_t off = 0;
  auto alloc = [&](size_t bytes) {
    void* p = ws + off;
    off += (bytes + 255) & ~(size_t)255;
    return p;
  };
  bf16* E     = (bf16*)alloc(4096ull * 4096 * 2);   // emb @ We^T, gate-interleaved
  bf16* Xz    = (bf16*)alloc(4096ull * 4096 * 2);   // z @ Wcih^T, gate-interleaved
  float* cdec = (float*)alloc(4096ull * 1024 * 4);
  bf16* Abuf  = (bf16*)alloc(4096ull * 1536 * 2);   // [note(512) | h(1024)]
  bf16* Wd    = (bf16*)alloc(4096ull * 1536 * 2);   // P-packed [Wih_note | Whh]
  bf16* We    = (bf16*)alloc(4096ull * 1024 * 2);   // P-packed Wih_emb
  bf16* Wcih  = (bf16*)alloc(4096ull * 512 * 2);    // P-packed
  bf16* Wchh  = (bf16*)alloc(4096ull * 1024 * 2);   // P-packed
  bf16* Wo    = (bf16*)alloc(512ull * 1024 * 2);
  float* cc   = (float*)alloc(256ull * 1024 * 4);
  bf16* emb   = (bf16*)alloc(4096ull * 1024 * 2);
  bf16* Zb    = (bf16*)alloc(4096ull * 512 * 2);
  bf16* hz0   = (bf16*)alloc(256ull * 1024 * 2);
  float* bdP  = (float*)alloc(4096ull * 4);
  float* bcP  = (float*)alloc(4096ull * 4);

  dim3 b256(256);

  hipFuncSetAttribute(reinterpret_cast<const void*>(&gemm8<0>),
                      hipFuncAttributeMaxDynamicSharedMemorySize, 131072);
  hipFuncSetAttribute(reinterpret_cast<const void*>(&gemm8<1>),
                      hipFuncAttributeMaxDynamicSharedMemorySize, 131072);

  // packing
  pack_w_perm<<<4096 * 512 / 256, b256, 0, stream>>>(cond_Wih, Wcih, 512);
  pack_w_perm<<<4096 * 1024 / 256, b256, 0, stream>>>(cond_Whh, Wchh, 1024);
  conv_f32_bf16<<<(512 * 1024 + 255) / 256, b256, 0, stream>>>(out_W, Wo, 512 * 1024);
  pack_w_dec<<<4096 * 1536 / 256, b256, 0, stream>>>(dec_Wih, dec_Whh, Wd);
  pack_w_emb<<<4096 * 1024 / 256, b256, 0, stream>>>(dec_Wih, We);
  pack_bias<<<16, b256, 0, stream>>>(dec_bih, dec_bhh, bdP);
  pack_bias<<<16, b256, 0, stream>>>(cond_bih, cond_bhh, bcP);
  pack_zb<<<4096 * 512 / 256, b256, 0, stream>>>(z, Zb);
  init_cond<<<256 * 1024 / 256, b256, 0, stream>>>(cc, hz0);
  init_state<<<4096 * 1536 / 256, b256, 0, stream>>>(dec_h0, dec_c0, Abuf, cdec);

  // Xz = Zb @ Wcih^T (bf16, gate-interleaved), 8-phase
  gemm8<0><<<256, 512, 131072, stream>>>(Zb, 512, Wcih, 512, Xz,
                                         nullptr, nullptr, nullptr, nullptr, 0);

  // conductor chain: 16 sequential fused steps (M=256)
  for (int l = 0; l < 16; ++l) {
    const bf16* hprev = (l == 0) ? hz0 : (emb + (size_t)(l - 1) * 256 * 1024);
    gemm_cell<32, 2, 2, 2><<<dim3(32, 8), dim3(256), 0, stream>>>(
        hprev, 1024, Wchh, Xz + (size_t)l * 256 * 4096, bcP,
        cc, emb + (size_t)l * 256 * 1024, 1024, 1024);
  }

  // E = emb @ We^T (bf16, gate-interleaved), 8-phase
  gemm8<0><<<256, 512, 131072, stream>>>(emb, 1024, We, 1024, E,
                                         nullptr, nullptr, nullptr, nullptr, 0);

  // 16 autoregressive decoder steps (M = 4096), fused 8-phase GEMM+cell
  for (int n = 0; n < 16; ++n) {
    gemm8<1><<<256, 512, 131072, stream>>>(Abuf, 1536, Wd, 1536, nullptr,
                                           E, bdP, cdec, Abuf + 512, 1536);
    gemm_bt<128, 64, 2, 2, 1><<<dim3(512 / 64, 4096 / 128), dim3(256), 0, stream>>>(
        Abuf + 512, 1536, Wo, 1024, nullptr, 0, 1024, out_b, out, Abuf, n);
  }
}